// Round 3
// baseline (345.636 us; speedup 1.0000x reference)
//
#include <hip/hip_runtime.h>
#include <hip/hip_cooperative_groups.h>

namespace cg = cooperative_groups;

#define HDIM 128
#define BDIM 512
#define PM (BDIM * HDIM)          // 65536 floats per [B,H] matrix
#define NSL_T 16                  // teacher K=2048 -> 16 slices of 128
#define NSL_S 6                   // student K=768  -> 6 slices of 128
#define NTASKA ((NSL_T + NSL_S) * (BDIM / 8))   // 22 * 64 = 1408

// Single fused cooperative kernel: proj -> UV -> pair -> reduce.
// grid 256 blocks x 512 threads (8 waves/CU, 1 block/CU).
__global__ __launch_bounds__(512, 2) void fused_kernel(
    const float* __restrict__ Ft, const float* __restrict__ Fs,
    const float* __restrict__ Wt, const float* __restrict__ bt,
    const float* __restrict__ Ws, const float* __restrict__ bs,
    const float* __restrict__ W1, const float* __restrict__ b1,
    const float* __restrict__ W2, const float* __restrict__ b2,
    float* __restrict__ Ppt, float* __restrict__ Pps,
    float* __restrict__ Ut, float* __restrict__ Vt,
    float* __restrict__ Us, float* __restrict__ Vs,
    float* __restrict__ partial, float* __restrict__ out)
{
    // 37376 B: stage A uses [0, 4096) floats; stage C uses full layout below.
    __shared__ alignas(16) float smem[9344];
    const int tid = threadIdx.x;
    const int bid = blockIdx.x;
    cg::grid_group grid = cg::this_grid();

    // ---------------- Stage A: projection partials ----------------
    // task t: slice = t>>6 (22 slices of 128 cols), rowgroup rg = t&63 (8 rows).
    // 4 sub-blocks of 128 threads; slot x = 4*bid + s, stride 1024.
    // Trip count: 2nd iter iff x < 384 <=> bid <= 95 for ALL s -> __syncthreads safe.
    {
        const int s = tid >> 7, h = tid & 127;
        float* fbA = smem + s * (8 * HDIM);
        for (int t = bid * 4 + s; t < NTASKA; t += 1024) {
            const int slice = t >> 6, rg = t & 63;
            const float* F; const float* W; float* P; int K, sl;
            if (slice < NSL_T) { F = Ft; W = Wt; K = 2048; sl = slice;         P = Ppt + (size_t)sl * PM; }
            else               { F = Fs; W = Ws; K = 768;  sl = slice - NSL_T; P = Pps + (size_t)sl * PM; }
            const int c0 = sl * 128;
            const int row0 = rg * 8;
            __syncthreads();
            #pragma unroll
            for (int r = 0; r < 8; ++r)
                fbA[r * HDIM + h] = F[(size_t)(row0 + r) * K + c0 + h];
            __syncthreads();
            float acc[8] = {0.f,0.f,0.f,0.f,0.f,0.f,0.f,0.f};
            const float4* fb4 = (const float4*)fbA;
            #pragma unroll 4
            for (int k4 = 0; k4 < 32; ++k4) {
                const float* wp = W + (size_t)(c0 + 4 * k4) * HDIM + h;
                float w0 = wp[0], w1 = wp[HDIM], w2 = wp[2 * HDIM], w3 = wp[3 * HDIM];
                #pragma unroll
                for (int r = 0; r < 8; ++r) {
                    float4 f = fb4[r * 32 + k4];
                    acc[r] = fmaf(f.x, w0, fmaf(f.y, w1, fmaf(f.z, w2, fmaf(f.w, w3, acc[r]))));
                }
            }
            float* Pr = P + (size_t)row0 * HDIM + h;
            #pragma unroll
            for (int r = 0; r < 8; ++r) Pr[r * HDIM] = acc[r];
        }
    }
    __threadfence();
    grid.sync();

    // ---------------- Stage B: slice-sum + bias, U/V matmul ----------------
    // 256 blocks = 256 tasks (net = bid>>7, rowgroup of 4 rows = bid&127).
    // quarters q: q<2 -> U rows {2q_lo,2q_lo+1}; q>=2 -> V.
    {
        const int h = tid & 127, q = tid >> 7;
        const int net = bid >> 7, rg = bid & 127;
        const float* Pp; const float* bb; float* U; float* V; int ns;
        if (net == 0) { Pp = Ppt; bb = bt; U = Ut; V = Vt; ns = NSL_T; }
        else          { Pp = Pps; bb = bs; U = Us; V = Vs; ns = NSL_S; }
        const int row0 = rg * 4;
        float accs = bb[h];
        for (int sl = 0; sl < ns; ++sl)
            accs += Pp[(size_t)sl * PM + (size_t)(row0 + q) * HDIM + h];
        smem[q * HDIM + h] = accs;
        __syncthreads();
        const int uv = q >> 1, rp = q & 1;
        float a0 = 0.f, a1 = 0.f;
        const float4* sb4 = (const float4*)smem;
        #pragma unroll 4
        for (int k4 = 0; k4 < 32; ++k4) {
            const float* wp = W1 + (size_t)(uv * HDIM + 4 * k4) * HDIM + h;
            float w0 = wp[0], w1 = wp[HDIM], w2 = wp[2 * HDIM], w3 = wp[3 * HDIM];
            float4 f0 = sb4[(2 * rp + 0) * 32 + k4];
            float4 f1 = sb4[(2 * rp + 1) * 32 + k4];
            a0 = fmaf(f0.x, w0, fmaf(f0.y, w1, fmaf(f0.z, w2, fmaf(f0.w, w3, a0))));
            a1 = fmaf(f1.x, w0, fmaf(f1.y, w1, fmaf(f1.z, w2, fmaf(f1.w, w3, a1))));
        }
        float* O = (uv == 0) ? U : V;
        float badd = (uv == 0) ? b1[h] : 0.f;
        O[(size_t)(row0 + 2 * rp + 0) * HDIM + h] = a0 + badd;
        O[(size_t)(row0 + 2 * rp + 1) * HDIM + h] = a1 + badd;
    }
    __threadfence();
    grid.sync();

    // ---------------- Stage C: pairwise relations, 32x32 tile/block ----------------
    {
        const int tx = tid & 15, ty = (tid >> 4) & 15, z = tid >> 8;
        const int i0 = (bid >> 4) * 32, j0 = (bid & 15) * 32;
        float4* lUt = (float4*)smem;          // 32*17 = 544 float4 each
        float4* lVt = lUt + 544;
        float4* lUs = lVt + 544;
        float4* lVs = lUs + 544;
        float4* w2s = lVs + 544;              // 32 float4
        float*  red = (float*)(w2s + 32);     // 512 floats

        const int iy = ty + 16 * z;
        const int fr = tid >> 4, fc = tid & 15;   // fill coords: 32 rows x 16 f4
        float aT0 = 0.f, aT1 = 0.f, aS0 = 0.f, aS1 = 0.f;

        for (int half = 0; half < 2; ++half) {
            __syncthreads();
            lUt[fr * 17 + fc] = ((const float4*)Ut)[(size_t)(i0 + fr) * 32 + half * 16 + fc];
            lVt[fr * 17 + fc] = ((const float4*)Vt)[(size_t)(j0 + fr) * 32 + half * 16 + fc];
            lUs[fr * 17 + fc] = ((const float4*)Us)[(size_t)(i0 + fr) * 32 + half * 16 + fc];
            lVs[fr * 17 + fc] = ((const float4*)Vs)[(size_t)(j0 + fr) * 32 + half * 16 + fc];
            if (half == 0 && tid < 32) w2s[tid] = ((const float4*)W2)[tid];
            __syncthreads();
            #pragma unroll 4
            for (int h4 = 0; h4 < 16; ++h4) {
                float4 w = w2s[half * 16 + h4];
                float4 u  = lUt[iy * 17 + h4];
                float4 pp = lUs[iy * 17 + h4];
                float4 v0 = lVt[tx * 17 + h4],        v1 = lVt[(tx + 16) * 17 + h4];
                float4 q0 = lVs[tx * 17 + h4],        q1 = lVs[(tx + 16) * 17 + h4];
                aT0 = fmaf(fmaxf(u.x + v0.x, 0.f), w.x, fmaf(fmaxf(u.y + v0.y, 0.f), w.y,
                      fmaf(fmaxf(u.z + v0.z, 0.f), w.z, fmaf(fmaxf(u.w + v0.w, 0.f), w.w, aT0))));
                aT1 = fmaf(fmaxf(u.x + v1.x, 0.f), w.x, fmaf(fmaxf(u.y + v1.y, 0.f), w.y,
                      fmaf(fmaxf(u.z + v1.z, 0.f), w.z, fmaf(fmaxf(u.w + v1.w, 0.f), w.w, aT1))));
                aS0 = fmaf(fmaxf(pp.x + q0.x, 0.f), w.x, fmaf(fmaxf(pp.y + q0.y, 0.f), w.y,
                      fmaf(fmaxf(pp.z + q0.z, 0.f), w.z, fmaf(fmaxf(pp.w + q0.w, 0.f), w.w, aS0))));
                aS1 = fmaf(fmaxf(pp.x + q1.x, 0.f), w.x, fmaf(fmaxf(pp.y + q1.y, 0.f), w.y,
                      fmaf(fmaxf(pp.z + q1.z, 0.f), w.z, fmaf(fmaxf(pp.w + q1.w, 0.f), w.w, aS1))));
            }
        }

        const float b2v = b2[0];
        float local = 0.f;
        const int i = i0 + iy;
        {
            int j = j0 + tx;
            if (i != j) {
                float tr = 1.f / (1.f + __expf(-(aT0 + b2v)));
                float sr = 1.f / (1.f + __expf(-(aS0 + b2v)));
                float d = sr - tr;
                local = fmaf(d, d, local);
            }
        }
        {
            int j = j0 + tx + 16;
            if (i != j) {
                float tr = 1.f / (1.f + __expf(-(aT1 + b2v)));
                float sr = 1.f / (1.f + __expf(-(aS1 + b2v)));
                float d = sr - tr;
                local = fmaf(d, d, local);
            }
        }
        red[tid] = local;
        __syncthreads();
        #pragma unroll
        for (int st = 256; st > 0; st >>= 1) {
            if (tid < st) red[tid] += red[tid + st];
            __syncthreads();
        }
        if (tid == 0) partial[bid] = red[0];
    }
    __threadfence();
    grid.sync();

    // ---------------- Stage D: final reduce in block 0 ----------------
    if (bid == 0) {
        float* red = (float*)(((float4*)smem) + 2208);
        red[tid] = (tid < 256) ? partial[tid] : 0.f;
        __syncthreads();
        #pragma unroll
        for (int st = 256; st > 0; st >>= 1) {
            if (tid < st) red[tid] += red[tid + st];
            __syncthreads();
        }
        if (tid == 0) out[0] = red[0] * (1.0f / ((float)BDIM * (float)BDIM));
    }
}

extern "C" void kernel_launch(void* const* d_in, const int* in_sizes, int n_in,
                              void* d_out, int out_size, void* d_ws, size_t ws_size,
                              hipStream_t stream) {
    const float* teacher = (const float*)d_in[0];   // [512,2048]
    const float* student = (const float*)d_in[1];   // [512,768]
    const float* Wt = (const float*)d_in[2];        // [2048,128]
    const float* bt = (const float*)d_in[3];        // [128]
    const float* Ws = (const float*)d_in[4];        // [768,128]
    const float* bs = (const float*)d_in[5];        // [128]
    const float* W1 = (const float*)d_in[6];        // [256,128]
    const float* b1 = (const float*)d_in[7];        // [128]
    const float* W2 = (const float*)d_in[8];        // [128,1]
    const float* b2 = (const float*)d_in[9];        // [1]
    float* out = (float*)d_out;

    float* ws = (float*)d_ws;
    float* Ppt = ws;                       // [16][512][128]
    float* Pps = Ppt + (size_t)NSL_T * PM; // [6][512][128]
    float* Ut  = Pps + (size_t)NSL_S * PM;
    float* Vt  = Ut + PM;
    float* Us  = Vt + PM;
    float* Vs  = Us + PM;
    float* partial = Vs + PM;              // [256]

    void* args[] = { (void*)&teacher, (void*)&student, (void*)&Wt, (void*)&bt,
                     (void*)&Ws, (void*)&bs, (void*)&W1, (void*)&b1,
                     (void*)&W2, (void*)&b2,
                     (void*)&Ppt, (void*)&Pps, (void*)&Ut, (void*)&Vt,
                     (void*)&Us, (void*)&Vs, (void*)&partial, (void*)&out };

    hipLaunchCooperativeKernel((const void*)fused_kernel, dim3(256), dim3(512),
                               args, 0, stream);
}

// Round 4
// 119.905 us; speedup vs baseline: 2.8826x; 2.8826x over previous
//
#include <hip/hip_runtime.h>

#define HDIM 128
#define BDIM 512
#define PM (BDIM * HDIM)   // 65536 floats per [B,H] matrix
#define NSL_T 16           // teacher K=2048 -> 16 slices of 128
#define NSL_S 6            // student K=768  -> 6 slices of 128

// ---------------- Kernel 1: projection partials, no atomics.
// grid: (B/8, NSL_T+NSL_S). y<16 -> teacher slice y; y>=16 -> student slice y-16.
// block: 128 threads (h). Each block: one 128-col K-slice x 8 rows.
// W element reuse = 8 FMA per load; F tile in LDS read as wave-uniform broadcast.
__global__ __launch_bounds__(128) void proj_kernel(
    const float* __restrict__ Ft, const float* __restrict__ Fs,
    const float* __restrict__ Wt, const float* __restrict__ Ws,
    float* __restrict__ Ppt, float* __restrict__ Pps)
{
    __shared__ alignas(16) float fb[8 * HDIM];
    const int h = threadIdx.x;
    const int row0 = blockIdx.x * 8;

    const float* F; const float* W; float* P; int K, sl;
    if (blockIdx.y < NSL_T) { F = Ft; W = Wt; K = 2048; sl = blockIdx.y;         P = Ppt + (size_t)sl * PM; }
    else                    { F = Fs; W = Ws; K = 768;  sl = blockIdx.y - NSL_T; P = Pps + (size_t)sl * PM; }
    const int c0 = sl * 128;

    #pragma unroll
    for (int r = 0; r < 8; ++r)
        fb[r * HDIM + h] = F[(size_t)(row0 + r) * K + c0 + h];
    __syncthreads();

    float acc[8] = {0.f,0.f,0.f,0.f,0.f,0.f,0.f,0.f};
    const float4* fb4 = (const float4*)fb;
    #pragma unroll 4
    for (int k4 = 0; k4 < 32; ++k4) {
        const float* wp = W + (size_t)(c0 + 4 * k4) * HDIM + h;
        float w0 = wp[0], w1 = wp[HDIM], w2 = wp[2 * HDIM], w3 = wp[3 * HDIM];
        #pragma unroll
        for (int r = 0; r < 8; ++r) {
            float4 f = fb4[r * 32 + k4];
            acc[r] = fmaf(f.x, w0, fmaf(f.y, w1, fmaf(f.z, w2, fmaf(f.w, w3, acc[r]))));
        }
    }
    float* Pr = P + (size_t)row0 * HDIM + h;
    #pragma unroll
    for (int r = 0; r < 8; ++r) Pr[r * HDIM] = acc[r];
}

// ---------------- Kernel 2: slice-sum + bias, then U = P@W1a + b1, V = P@W1b.
// grid: (B/4, 2), block 128. Also zero-inits out[0] (runs before pair_kernel).
__global__ __launch_bounds__(128) void uv_kernel(
    const float* __restrict__ Ppt, const float* __restrict__ Pps,
    const float* __restrict__ bt, const float* __restrict__ bs,
    const float* __restrict__ W1, const float* __restrict__ b1,
    float* __restrict__ Ut, float* __restrict__ Vt,
    float* __restrict__ Us, float* __restrict__ Vs,
    float* __restrict__ out)
{
    if (blockIdx.x == 0 && blockIdx.y == 0 && threadIdx.x == 0)
        out[0] = 0.f;   // zero the atomic target for pair_kernel (stream-ordered)

    const float* Pp; const float* bb; float* U; float* V; int ns;
    if (blockIdx.y == 0) { Pp = Ppt; bb = bt; U = Ut; V = Vt; ns = NSL_T; }
    else                 { Pp = Pps; bb = bs; U = Us; V = Vs; ns = NSL_S; }

    __shared__ alignas(16) float fbuf[4][HDIM];
    const int h = threadIdx.x;
    const int row0 = blockIdx.x * 4;

    #pragma unroll
    for (int r = 0; r < 4; ++r) {
        float acc = bb[h];
        for (int s = 0; s < ns; ++s)
            acc += Pp[(size_t)s * PM + (size_t)(row0 + r) * HDIM + h];
        fbuf[r][h] = acc;
    }
    __syncthreads();

    float au[4] = {0.f, 0.f, 0.f, 0.f};
    float av[4] = {0.f, 0.f, 0.f, 0.f};

    const float4* fb0 = (const float4*)fbuf[0];
    const float4* fb1 = (const float4*)fbuf[1];
    const float4* fb2 = (const float4*)fbuf[2];
    const float4* fb3 = (const float4*)fbuf[3];

    #pragma unroll 2
    for (int c4 = 0; c4 < HDIM / 4; ++c4) {
        float f[4][4];
        *(float4*)f[0] = fb0[c4];
        *(float4*)f[1] = fb1[c4];
        *(float4*)f[2] = fb2[c4];
        *(float4*)f[3] = fb3[c4];
        #pragma unroll
        for (int q = 0; q < 4; ++q) {
            int k = 4 * c4 + q;
            float wu = W1[(size_t)k * HDIM + h];
            float wv = W1[(size_t)(HDIM + k) * HDIM + h];
            #pragma unroll
            for (int r = 0; r < 4; ++r) {
                au[r] = fmaf(f[r][q], wu, au[r]);
                av[r] = fmaf(f[r][q], wv, av[r]);
            }
        }
    }

    float bb1 = b1[h];
    #pragma unroll
    for (int r = 0; r < 4; ++r) {
        U[(size_t)(row0 + r) * HDIM + h] = au[r] + bb1;
        V[(size_t)(row0 + r) * HDIM + h] = av[r];
    }
}

// ---------------- Kernel 3: pairwise relations, 2x2 register blocking,
// one atomicAdd per block onto out (zeroed by uv_kernel).
// grid: (16,16) -> 32x32 pair tiles. block (16,16).
__global__ __launch_bounds__(256) void pair_kernel(
    const float* __restrict__ Ut, const float* __restrict__ Vt,
    const float* __restrict__ Us, const float* __restrict__ Vs,
    const float* __restrict__ W2, const float* __restrict__ b2,
    float* __restrict__ out)
{
    // 32 rows x 16 float4 per chunk, stride 17 -> conflict-free V reads
    __shared__ alignas(16) float4 tUt[32 * 17];
    __shared__ alignas(16) float4 tVt[32 * 17];
    __shared__ alignas(16) float4 tUs[32 * 17];
    __shared__ alignas(16) float4 tVs[32 * 17];
    __shared__ alignas(16) float4 w2s[32];
    __shared__ float red[256];

    const int tx = threadIdx.x, ty = threadIdx.y;
    const int tid = ty * 16 + tx;
    const int i0 = blockIdx.y * 32, j0 = blockIdx.x * 32;

    const float4* Ut4 = (const float4*)Ut;
    const float4* Vt4 = (const float4*)Vt;
    const float4* Us4 = (const float4*)Us;
    const float4* Vs4 = (const float4*)Vs;

    if (tid < 32) w2s[tid] = ((const float4*)W2)[tid];

    float aT[2][2] = {{0.f, 0.f}, {0.f, 0.f}};
    float aS[2][2] = {{0.f, 0.f}, {0.f, 0.f}};

    for (int half = 0; half < 2; ++half) {
        const int c0 = half * 16;
        __syncthreads();
        #pragma unroll
        for (int it = 0; it < 2; ++it) {
            int fi = tid + 256 * it;           // 0..511
            int r = fi >> 4, c = fi & 15;      // 32 rows x 16 float4
            tUt[r * 17 + c] = Ut4[(size_t)(i0 + r) * 32 + c0 + c];
            tVt[r * 17 + c] = Vt4[(size_t)(j0 + r) * 32 + c0 + c];
            tUs[r * 17 + c] = Us4[(size_t)(i0 + r) * 32 + c0 + c];
            tVs[r * 17 + c] = Vs4[(size_t)(j0 + r) * 32 + c0 + c];
        }
        __syncthreads();

        #pragma unroll 4
        for (int h4 = 0; h4 < 16; ++h4) {
            float4 w = w2s[c0 + h4];
            float4 u[2], v[2], p[2], q[2];
            u[0] = tUt[ty * 17 + h4];        u[1] = tUt[(ty + 16) * 17 + h4];
            v[0] = tVt[tx * 17 + h4];        v[1] = tVt[(tx + 16) * 17 + h4];
            p[0] = tUs[ty * 17 + h4];        p[1] = tUs[(ty + 16) * 17 + h4];
            q[0] = tVs[tx * 17 + h4];        q[1] = tVs[(tx + 16) * 17 + h4];
            #pragma unroll
            for (int a = 0; a < 2; ++a)
                #pragma unroll
                for (int b = 0; b < 2; ++b) {
                    aT[a][b] = fmaf(fmaxf(u[a].x + v[b].x, 0.f), w.x,
                               fmaf(fmaxf(u[a].y + v[b].y, 0.f), w.y,
                               fmaf(fmaxf(u[a].z + v[b].z, 0.f), w.z,
                               fmaf(fmaxf(u[a].w + v[b].w, 0.f), w.w, aT[a][b]))));
                    aS[a][b] = fmaf(fmaxf(p[a].x + q[b].x, 0.f), w.x,
                               fmaf(fmaxf(p[a].y + q[b].y, 0.f), w.y,
                               fmaf(fmaxf(p[a].z + q[b].z, 0.f), w.z,
                               fmaf(fmaxf(p[a].w + q[b].w, 0.f), w.w, aS[a][b]))));
                }
        }
    }

    const float b2v = b2[0];
    float local = 0.f;
    #pragma unroll
    for (int a = 0; a < 2; ++a)
        #pragma unroll
        for (int b = 0; b < 2; ++b) {
            int i = i0 + ty + 16 * a;
            int j = j0 + tx + 16 * b;
            if (i != j) {
                float tr = 1.f / (1.f + __expf(-(aT[a][b] + b2v)));
                float sr = 1.f / (1.f + __expf(-(aS[a][b] + b2v)));
                float d = sr - tr;
                local = fmaf(d, d, local);
            }
        }

    red[tid] = local;
    __syncthreads();
    #pragma unroll
    for (int s = 128; s > 0; s >>= 1) {
        if (tid < s) red[tid] += red[tid + s];
        __syncthreads();
    }
    if (tid == 0)
        atomicAdd(out, red[0] * (1.0f / ((float)BDIM * (float)BDIM)));
}

extern "C" void kernel_launch(void* const* d_in, const int* in_sizes, int n_in,
                              void* d_out, int out_size, void* d_ws, size_t ws_size,
                              hipStream_t stream) {
    const float* teacher = (const float*)d_in[0];   // [512,2048]
    const float* student = (const float*)d_in[1];   // [512,768]
    const float* Wt = (const float*)d_in[2];        // [2048,128]
    const float* bt = (const float*)d_in[3];        // [128]
    const float* Ws = (const float*)d_in[4];        // [768,128]
    const float* bs = (const float*)d_in[5];        // [128]
    const float* W1 = (const float*)d_in[6];        // [256,128]
    const float* b1 = (const float*)d_in[7];        // [128]
    const float* W2 = (const float*)d_in[8];        // [128,1]
    const float* b2 = (const float*)d_in[9];        // [1]
    float* out = (float*)d_out;

    float* ws = (float*)d_ws;
    float* Ppt = ws;                        // [16][512][128]
    float* Pps = Ppt + (size_t)NSL_T * PM;  // [6][512][128]
    float* Ut  = Pps + (size_t)NSL_S * PM;
    float* Vt  = Ut + PM;
    float* Us  = Vt + PM;
    float* Vs  = Us + PM;

    proj_kernel<<<dim3(BDIM / 8, NSL_T + NSL_S), 128, 0, stream>>>(
        teacher, student, Wt, Ws, Ppt, Pps);

    uv_kernel<<<dim3(BDIM / 4, 2), 128, 0, stream>>>(Ppt, Pps, bt, bs, W1, b1,
                                                     Ut, Vt, Us, Vs, out);

    pair_kernel<<<dim3(16, 16), dim3(16, 16), 0, stream>>>(
        Ut, Vt, Us, Vs, W2, b2, out);
}